// Round 1
// baseline (223.644 us; speedup 1.0000x reference)
//
#include <hip/hip_runtime.h>

#define NQ    14
#define DIM   16384      // 2^14
#define NPAR  196        // 4*3*14 + 2*14
#define NCLS  10
#define BLK   1024
#define NWAVE (BLK / 64)

// Apply a fused 2x2 complex unitary on bit position `bit` (stride = 1<<bit).
__device__ __forceinline__ void apply1q(float* sr, float* si, int bit,
    float r00, float i00, float r01, float i01,
    float r10, float i10, float r11, float i11, int tid)
{
    const int stride = 1 << bit;
    #pragma unroll
    for (int j = 0; j < DIM / 2 / BLK; ++j) {
        int k   = tid + j * BLK;
        int low = k & (stride - 1);
        int i0  = ((k - low) << 1) | low;   // insert 0 at `bit`
        int i1  = i0 + stride;
        float a0r = sr[i0], a0i = si[i0];
        float a1r = sr[i1], a1i = si[i1];
        float n0r = r00 * a0r - i00 * a0i + r01 * a1r - i01 * a1i;
        float n0i = r00 * a0i + i00 * a0r + r01 * a1i + i01 * a1r;
        float n1r = r10 * a0r - i10 * a0i + r11 * a1r - i11 * a1i;
        float n1i = r10 * a0i + i10 * a0r + r11 * a1i + i11 * a1r;
        sr[i0] = n0r; si[i0] = n0i;
        sr[i1] = n1r; si[i1] = n1i;
    }
}

// CNOT with control bit = tb+1, target bit = tb (adjacent bits).
__device__ __forceinline__ void applyCnot(float* sr, float* si, int tb, int tid)
{
    const int stride = 1 << tb;
    #pragma unroll
    for (int j = 0; j < DIM / 4 / BLK; ++j) {
        int k    = tid + j * BLK;
        int low  = k & (stride - 1);
        int high = k - low;                       // bits >= tb of k
        int i0   = (high << 2) | (stride << 1) | low; // control=1, target=0
        int i1   = i0 | stride;                        // control=1, target=1
        float tr = sr[i0]; sr[i0] = sr[i1]; sr[i1] = tr;
        float ti = si[i0]; si[i0] = si[i1]; si[i1] = ti;
    }
}

__global__ void __launch_bounds__(BLK)
qvc_kernel(const float* __restrict__ x, const float* __restrict__ W,
           const float* __restrict__ bias, float* __restrict__ out)
{
    __shared__ float sr[DIM];
    __shared__ float si[DIM];

    const int b   = blockIdx.x;
    const int tid = threadIdx.x;
    const float* xb = x + b * NPAR;

    // init |0...0>
    #pragma unroll
    for (int j = 0; j < DIM / BLK; ++j) {
        sr[tid + j * BLK] = 0.0f;
        si[tid + j * BLK] = 0.0f;
    }
    if (tid == 0) sr[0] = 1.0f;
    __syncthreads();

    int p = 0;
    for (int L = 0; L < 4; ++L) {
        for (int q = 0; q < NQ; ++q) {
            float h1 = 0.5f * xb[p], h2 = 0.5f * xb[p + 1], h3 = 0.5f * xb[p + 2];
            p += 3;
            float s1, c1, s2, c2, s3, c3;
            sincosf(h1, &s1, &c1);
            sincosf(h2, &s2, &c2);
            sincosf(h3, &s3, &c3);
            // A = Ry(h2*2) * Rx(h1*2)
            float A00r =  c2 * c1, A00i =  s2 * s1;
            float A01r = -s2 * c1, A01i = -c2 * s1;
            float A10r =  s2 * c1, A10i = -c2 * s1;
            float A11r =  c2 * c1, A11i = -s2 * s1;
            // U = Rz * A : row0 *= (c3 - i s3), row1 *= (c3 + i s3)
            float U00r = c3 * A00r + s3 * A00i, U00i = c3 * A00i - s3 * A00r;
            float U01r = c3 * A01r + s3 * A01i, U01i = c3 * A01i - s3 * A01r;
            float U10r = c3 * A10r - s3 * A10i, U10i = c3 * A10i + s3 * A10r;
            float U11r = c3 * A11r - s3 * A11i, U11i = c3 * A11i + s3 * A11r;
            apply1q(sr, si, 13 - q, U00r, U00i, U01r, U01i, U10r, U10i, U11r, U11i, tid);
            __syncthreads();
        }
        for (int q = 0; q < NQ - 1; ++q) {
            // control qubit q (bit 13-q), target qubit q+1 (bit 12-q)
            applyCnot(sr, si, 12 - q, tid);
            __syncthreads();
        }
    }
    // final RX, RY per qubit
    for (int q = 0; q < NQ; ++q) {
        float h1 = 0.5f * xb[p], h2 = 0.5f * xb[p + 1];
        p += 2;
        float s1, c1, s2, c2;
        sincosf(h1, &s1, &c1);
        sincosf(h2, &s2, &c2);
        float A00r =  c2 * c1, A00i =  s2 * s1;
        float A01r = -s2 * c1, A01i = -c2 * s1;
        float A10r =  s2 * c1, A10i = -c2 * s1;
        float A11r =  c2 * c1, A11i = -s2 * s1;
        apply1q(sr, si, 13 - q, A00r, A00i, A01r, A01i, A10r, A10i, A11r, A11i, tid);
        __syncthreads();
    }

    // per-bit-position signed probability sums: e[bp], qubit q -> bp = 13-q
    float e[NQ];
    #pragma unroll
    for (int bp = 0; bp < NQ; ++bp) e[bp] = 0.0f;
    #pragma unroll
    for (int j = 0; j < DIM / BLK; ++j) {
        int i = tid + j * BLK;
        float pr = sr[i] * sr[i] + si[i] * si[i];
        #pragma unroll
        for (int bp = 0; bp < NQ; ++bp)
            e[bp] += (i & (1 << bp)) ? -pr : pr;
    }
    __syncthreads();   // everyone done reading sr/si; reuse sr as scratch

    // wave-level reduce (64 lanes)
    #pragma unroll
    for (int bp = 0; bp < NQ; ++bp) {
        float v = e[bp];
        #pragma unroll
        for (int off = 32; off > 0; off >>= 1) v += __shfl_down(v, off, 64);
        e[bp] = v;
    }
    const int wave = tid >> 6, lane = tid & 63;
    float* red = sr;   // reuse: NWAVE*NQ = 224 floats
    if (lane == 0) {
        #pragma unroll
        for (int bp = 0; bp < NQ; ++bp) red[wave * NQ + bp] = e[bp];
    }
    __syncthreads();

    if (tid < NCLS) {
        float acc = bias[tid];
        #pragma unroll
        for (int q = 0; q < NQ; ++q) {
            int bp = 13 - q;
            float eq = 0.0f;
            #pragma unroll
            for (int w = 0; w < NWAVE; ++w) eq += red[w * NQ + bp];
            acc += W[tid * NQ + q] * eq;
        }
        out[b * NCLS + tid] = acc;
    }
}

extern "C" void kernel_launch(void* const* d_in, const int* in_sizes, int n_in,
                              void* d_out, int out_size, void* d_ws, size_t ws_size,
                              hipStream_t stream)
{
    const float* x    = (const float*)d_in[0];   // (64, 196)
    const float* W    = (const float*)d_in[1];   // (10, 14)
    const float* bias = (const float*)d_in[2];   // (10,)
    float*       out  = (float*)d_out;           // (64, 10)

    hipLaunchKernelGGL(qvc_kernel, dim3(64), dim3(BLK), 0, stream, x, W, bias, out);
}

// Round 2
// 191.188 us; speedup vs baseline: 1.1698x; 1.1698x over previous
//
#include <hip/hip_runtime.h>

#define NQ     14
#define DIM    16384
#define NPAR   196
#define NCLS   10
#define BLK    1024
#define NGATES 70

// ---------- compile-time gate masks ----------
// We store d[j] = s_ref[P(j)] with P linear over GF(2)^14, never moving data
// for CNOT chains (each chain: s'[i] = s[i ^ (i>>1)], so P <- h^-1 o P).
// A rotation on circuit bit bp becomes: pair j <-> j^m (m = column bp of P^-1),
// role = parity(j & u) (u = row bp of P).
struct GateInfo { int m; int u; };
struct Tables { GateInfo g[NGATES]; int mu[NQ]; };

constexpr Tables make_tables() {
    Tables T{};
    unsigned m[NQ], u[NQ];
    for (int i = 0; i < NQ; ++i) { m[i] = 1u << i; u[i] = 1u << i; }
    int gi = 0;
    for (int L = 0; L < 4; ++L) {
        for (int q = 0; q < NQ; ++q) {
            int bp = 13 - q;
            T.g[gi].m = (int)m[bp]; T.g[gi].u = (int)u[bp]; ++gi;
        }
        // CNOT chain: P <- h^-1 o P ;  h(x) = x ^ (x>>1)
        unsigned nm[NQ], nu[NQ];
        nm[0] = m[0];
        for (int bp = 1; bp < NQ; ++bp) nm[bp] = m[bp] ^ m[bp - 1];   // P^-1 <- P^-1 o h
        unsigned acc = 0;
        for (int bp = NQ - 1; bp >= 0; --bp) { acc ^= u[bp]; nu[bp] = acc; } // suffix-xor rows
        for (int i = 0; i < NQ; ++i) { m[i] = nm[i]; u[i] = nu[i]; }
    }
    for (int q = 0; q < NQ; ++q) {
        int bp = 13 - q;
        T.g[gi].m = (int)m[bp]; T.g[gi].u = (int)u[bp]; ++gi;
    }
    for (int q = 0; q < NQ; ++q) T.mu[q] = (int)u[13 - q];  // measurement sign masks
    return T;
}
constexpr Tables TAB = make_tables();

// index layout: j = tid*16 + k  (k: bits 0-3 in regs, lane: bits 4-9, wave: bits 10-13)
__global__ void __launch_bounds__(BLK)
qvc_kernel(const float* __restrict__ x, const float* __restrict__ W,
           const float* __restrict__ bias, float* __restrict__ out)
{
    __shared__ __align__(16) float lr[DIM];
    __shared__ __align__(16) float li[DIM];
    __shared__ float uc[NGATES][8];

    const int b   = blockIdx.x;
    const int tid = threadIdx.x;
    const float* xb = x + b * NPAR;

    // ---- 1. cooperative gate-coefficient compute (one gate per thread) ----
    if (tid < NGATES) {
        int pidx, nang;
        if (tid < 56) { pidx = (tid / 14) * 42 + (tid % 14) * 3; nang = 3; }
        else          { pidx = 168 + (tid - 56) * 2;             nang = 2; }
        float a1 = 0.5f * xb[pidx], a2 = 0.5f * xb[pidx + 1];
        float s1, c1, s2, c2;
        sincosf(a1, &s1, &c1);
        sincosf(a2, &s2, &c2);
        // A = Ry * Rx
        float A00r =  c2 * c1, A00i =  s2 * s1;
        float A01r = -s2 * c1, A01i = -c2 * s1;
        float A10r =  s2 * c1, A10i = -c2 * s1;
        float A11r =  c2 * c1, A11i = -s2 * s1;
        float U0, U1, U2, U3, U4, U5, U6, U7;
        if (nang == 3) {
            float a3 = 0.5f * xb[pidx + 2]; float s3, c3; sincosf(a3, &s3, &c3);
            U0 = c3 * A00r + s3 * A00i; U1 = c3 * A00i - s3 * A00r;
            U2 = c3 * A01r + s3 * A01i; U3 = c3 * A01i - s3 * A01r;
            U4 = c3 * A10r - s3 * A10i; U5 = c3 * A10i + s3 * A10r;
            U6 = c3 * A11r - s3 * A11i; U7 = c3 * A11i + s3 * A11r;
        } else {
            U0 = A00r; U1 = A00i; U2 = A01r; U3 = A01i;
            U4 = A10r; U5 = A10i; U6 = A11r; U7 = A11i;
        }
        uc[tid][0] = U0; uc[tid][1] = U1; uc[tid][2] = U2; uc[tid][3] = U3;
        uc[tid][4] = U4; uc[tid][5] = U5; uc[tid][6] = U6; uc[tid][7] = U7;
    }

    // ---- 2. init |0...0> in registers ----
    float ar[16], ai[16];
    #pragma unroll
    for (int k = 0; k < 16; ++k) { ar[k] = 0.0f; ai[k] = 0.0f; }
    if (tid == 0) ar[0] = 1.0f;
    __syncthreads();

    // ---- 3. the 70 generalized 1q gates ----
    #pragma unroll
    for (int g = 0; g < NGATES; ++g) {
        const int m = TAB.g[g].m;
        const int u = TAB.g[g].u;
        const float c00r = uc[g][0], c00i = uc[g][1], c01r = uc[g][2], c01i = uc[g][3];
        const float c10r = uc[g][4], c10i = uc[g][5], c11r = uc[g][6], c11i = uc[g][7];
        const bool rb = (__popc(tid & (u >> 4)) & 1) != 0;
        // coefficients by k-class (cls = parity(k & u & 15)); role = rb ^ cls
        const float D0r = rb ? c11r : c00r, D0i = rb ? c11i : c00i;
        const float O0r = rb ? c10r : c01r, O0i = rb ? c10i : c01i;
        const float D1r = rb ? c00r : c11r, D1i = rb ? c00i : c11i;
        const float O1r = rb ? c01r : c10r, O1i = rb ? c01i : c10i;

        float pr[16], pim[16];
        if (m < 16) {
            #pragma unroll
            for (int k = 0; k < 16; ++k) { pr[k] = ar[k ^ m]; pim[k] = ai[k ^ m]; }
        } else if (m < 1024) {
            const int lm = m >> 4, mr = m & 15;
            #pragma unroll
            for (int k = 0; k < 16; ++k) {
                pr[k]  = __shfl_xor(ar[k ^ mr], lm, 64);
                pim[k] = __shfl_xor(ai[k ^ mr], lm, 64);
            }
        } else {
            const int mr = m & 15;
            const int tp = tid ^ (m >> 4);
            __syncthreads();   // WAR: prior readers of lr/li done
            const int sw = (tid >> 1) & 3;
            float4* l4r = (float4*)lr;
            float4* l4i = (float4*)li;
            #pragma unroll
            for (int c = 0; c < 4; ++c) {
                l4r[tid * 4 + (c ^ sw)] = make_float4(ar[c*4+0], ar[c*4+1], ar[c*4+2], ar[c*4+3]);
                l4i[tid * 4 + (c ^ sw)] = make_float4(ai[c*4+0], ai[c*4+1], ai[c*4+2], ai[c*4+3]);
            }
            __syncthreads();
            const int swp = (tp >> 1) & 3;
            float vr[16], vi[16];
            #pragma unroll
            for (int c = 0; c < 4; ++c) {
                float4 t0 = l4r[tp * 4 + (c ^ swp)];
                vr[c*4+0] = t0.x; vr[c*4+1] = t0.y; vr[c*4+2] = t0.z; vr[c*4+3] = t0.w;
                float4 t1 = l4i[tp * 4 + (c ^ swp)];
                vi[c*4+0] = t1.x; vi[c*4+1] = t1.y; vi[c*4+2] = t1.z; vi[c*4+3] = t1.w;
            }
            #pragma unroll
            for (int k = 0; k < 16; ++k) { pr[k] = vr[k ^ mr]; pim[k] = vi[k ^ mr]; }
        }

        #pragma unroll
        for (int k = 0; k < 16; ++k) {
            const int cls = __popc(k & u & 15) & 1;   // compile-time
            const float Dr = cls ? D1r : D0r, Di = cls ? D1i : D0i;
            const float Or = cls ? O1r : O0r, Oi = cls ? O1i : O0i;
            float nr = Dr * ar[k] - Di * ai[k] + Or * pr[k] - Oi * pim[k];
            float ni = Dr * ai[k] + Di * ar[k] + Or * pim[k] + Oi * pr[k];
            ar[k] = nr; ai[k] = ni;
        }
    }

    // ---- 4. measurement: E_q = sum |amp|^2 * (-1)^parity(j & mu[q]) ----
    float e[NQ];
    #pragma unroll
    for (int q = 0; q < NQ; ++q) e[q] = 0.0f;
    #pragma unroll
    for (int k = 0; k < 16; ++k) {
        float p2 = ar[k] * ar[k] + ai[k] * ai[k];
        #pragma unroll
        for (int q = 0; q < NQ; ++q) {
            const int um = TAB.mu[q];
            if (__popc(k & um & 15) & 1) e[q] -= p2; else e[q] += p2;
        }
    }
    #pragma unroll
    for (int q = 0; q < NQ; ++q) {
        const int um = TAB.mu[q];
        float v = (__popc(tid & (um >> 4)) & 1) ? -e[q] : e[q];
        #pragma unroll
        for (int off = 32; off > 0; off >>= 1) v += __shfl_down(v, off, 64);
        e[q] = v;
    }
    __syncthreads();   // lr free for reuse
    const int wave = tid >> 6, lane = tid & 63;
    if (lane == 0) {
        #pragma unroll
        for (int q = 0; q < NQ; ++q) lr[wave * NQ + q] = e[q];
    }
    __syncthreads();
    if (tid < NCLS) {
        float acc = bias[tid];
        #pragma unroll
        for (int q = 0; q < NQ; ++q) {
            float eq = 0.0f;
            #pragma unroll
            for (int w = 0; w < 16; ++w) eq += lr[w * NQ + q];
            acc += W[tid * NQ + q] * eq;
        }
        out[b * NCLS + tid] = acc;
    }
}

extern "C" void kernel_launch(void* const* d_in, const int* in_sizes, int n_in,
                              void* d_out, int out_size, void* d_ws, size_t ws_size,
                              hipStream_t stream)
{
    const float* x    = (const float*)d_in[0];   // (64, 196)
    const float* W    = (const float*)d_in[1];   // (10, 14)
    const float* bias = (const float*)d_in[2];   // (10,)
    float*       out  = (float*)d_out;           // (64, 10)

    hipLaunchKernelGGL(qvc_kernel, dim3(64), dim3(BLK), 0, stream, x, W, bias, out);
}

// Round 3
// 175.056 us; speedup vs baseline: 1.2776x; 1.0921x over previous
//
#include <hip/hip_runtime.h>

#define NQ     14
#define DIM    16384
#define NPAR   196
#define NCLS   10
#define BLK    1024
#define NGATES 70

// ---------------- compile-time frame/gate tables ----------------
// Stored state d[h] = s_ref[A(h)], A linear over GF(2)^14.
//  - CNOT chain:  s' = s o g, g(i)=i^(i>>1)  =>  A <- g^-1 o A
//       columns of A^-1: m[bp] <- m[bp]^m[bp-1];  rows of A: u[bp] <- suffix-xor
//  - rotation on ref bit bp: pair h <-> h^m[bp], role = parity(h & u[bp])
//  - physical relabel d'[h]=d[sigma(h)] (bit swap) => m,u <- sigma(m),sigma(u)
// Per round: emit gates with no wave bits in m, then ONE sigma (bits 10-13 <-> 0-3),
// then the rest (provably local afterwards).
struct GateInfo { int m; int u; int slot; };
struct Tables { GateInfo g[NGATES]; int mu[NQ]; int swap_at[5]; bool valid; };

constexpr unsigned swapbits(unsigned v) {
    return ((v & 0xFu) << 10) | (v & 0x3F0u) | ((v >> 10) & 0xFu);
}

constexpr Tables make_tables() {
    Tables T{};
    T.valid = true;
    unsigned m[NQ], u[NQ];
    for (int i = 0; i < NQ; ++i) { m[i] = 1u << i; u[i] = 1u << i; }
    int gi = 0;
    for (int r = 0; r < 5; ++r) {
        bool done[NQ] = {};
        for (int q = 0; q < NQ; ++q) {            // phase 1: local now
            int bp = 13 - q;
            if ((m[bp] & 0x3C00u) == 0u) {
                T.g[gi].m = (int)m[bp]; T.g[gi].u = (int)u[bp];
                T.g[gi].slot = r * 14 + q;
                done[q] = true; ++gi;
            }
        }
        T.swap_at[r] = gi;
        if (r > 0 && T.swap_at[r] <= T.swap_at[r - 1]) T.valid = false;
        for (int i = 0; i < NQ; ++i) { m[i] = swapbits(m[i]); u[i] = swapbits(u[i]); }
        for (int q = 0; q < NQ; ++q) {            // phase 2: local after sigma
            if (!done[q]) {
                int bp = 13 - q;
                if ((m[bp] & 0x3C00u) != 0u) T.valid = false;
                T.g[gi].m = (int)m[bp]; T.g[gi].u = (int)u[bp];
                T.g[gi].slot = r * 14 + q;
                ++gi;
            }
        }
        if (r < 4) {                              // CNOT chain
            for (int bp = 13; bp >= 1; --bp) m[bp] ^= m[bp - 1];
            unsigned acc = 0;
            for (int bp = 13; bp >= 0; --bp) { acc ^= u[bp]; u[bp] = acc; }
        }
    }
    if (gi != NGATES) T.valid = false;
    for (int q = 0; q < NQ; ++q) T.mu[q] = (int)u[13 - q];
    return T;
}
constexpr Tables TAB = make_tables();
static_assert(TAB.valid, "gate schedule construction failed");

// index layout: h = tid*16 + k   (k: bits 0-3 regs, lane: bits 4-9, wave: bits 10-13)
__global__ void __launch_bounds__(BLK)
qvc_kernel(const float* __restrict__ x, const float* __restrict__ W,
           const float* __restrict__ bias, float* __restrict__ out)
{
    __shared__ __align__(16) float lr[DIM];
    __shared__ __align__(16) float li[DIM];
    __shared__ __align__(16) float uc[NGATES][8];

    const int b    = blockIdx.x;
    const int tid  = threadIdx.x;
    const int wave = tid >> 6, lane = tid & 63;
    const float* xb = x + b * NPAR;

    // ---- gate coefficients: one gate per thread ----
    if (tid < NGATES) {
        const int layer = tid / 14, q = tid % 14;
        const int  pidx = (layer < 4) ? layer * 42 + q * 3 : 168 + q * 2;
        float a1 = 0.5f * xb[pidx], a2 = 0.5f * xb[pidx + 1];
        float s1, c1, s2, c2;
        sincosf(a1, &s1, &c1);
        sincosf(a2, &s2, &c2);
        // A = Ry * Rx
        float A00r =  c2 * c1, A00i =  s2 * s1;
        float A01r = -s2 * c1, A01i = -c2 * s1;
        float A10r =  s2 * c1, A10i = -c2 * s1;
        float A11r =  c2 * c1, A11i = -s2 * s1;
        float U0, U1, U2, U3, U4, U5, U6, U7;
        if (layer < 4) {
            float a3 = 0.5f * xb[pidx + 2]; float s3, c3; sincosf(a3, &s3, &c3);
            U0 = c3 * A00r + s3 * A00i; U1 = c3 * A00i - s3 * A00r;
            U2 = c3 * A01r + s3 * A01i; U3 = c3 * A01i - s3 * A01r;
            U4 = c3 * A10r - s3 * A10i; U5 = c3 * A10i + s3 * A10r;
            U6 = c3 * A11r - s3 * A11i; U7 = c3 * A11i + s3 * A11r;
        } else {
            U0 = A00r; U1 = A00i; U2 = A01r; U3 = A01i;
            U4 = A10r; U5 = A10i; U6 = A11r; U7 = A11i;
        }
        uc[tid][0] = U0; uc[tid][1] = U1; uc[tid][2] = U2; uc[tid][3] = U3;
        uc[tid][4] = U4; uc[tid][5] = U5; uc[tid][6] = U6; uc[tid][7] = U7;
    }

    float ar[16], ai[16];
    #pragma unroll
    for (int k = 0; k < 16; ++k) { ar[k] = 0.0f; ai[k] = 0.0f; }
    if (tid == 0) ar[0] = 1.0f;
    __syncthreads();

    #pragma unroll
    for (int g = 0; g < NGATES; ++g) {
        // one physical relabel per round: bits {10..13} <-> {0..3}
        if (g == TAB.swap_at[0] || g == TAB.swap_at[1] || g == TAB.swap_at[2] ||
            g == TAB.swap_at[3] || g == TAB.swap_at[4]) {
            __syncthreads();   // prior readers of lr/li done
            #pragma unroll
            for (int k = 0; k < 16; ++k) {
                lr[wave * 1024 + k * 64 + lane] = ar[k];   // conflict-free: lanes contiguous
                li[wave * 1024 + k * 64 + lane] = ai[k];
            }
            __syncthreads();
            #pragma unroll
            for (int k = 0; k < 16; ++k) {
                ar[k] = lr[k * 1024 + wave * 64 + lane];   // conflict-free
                ai[k] = li[k * 1024 + wave * 64 + lane];
            }
        }

        const int m = TAB.g[g].m, u = TAB.g[g].u, slot = TAB.g[g].slot;
        const float4 c0 = *(const float4*)&uc[slot][0];  // {00r,00i,01r,01i}
        const float4 c1 = *(const float4*)&uc[slot][4];  // {10r,10i,11r,11i}
        const bool rb = (__popc(tid & (u >> 4)) & 1) != 0;
        const float D0r = rb ? c1.z : c0.x, D0i = rb ? c1.w : c0.y;
        const float O0r = rb ? c1.x : c0.z, O0i = rb ? c1.y : c0.w;
        const float D1r = rb ? c0.x : c1.z, D1i = rb ? c0.y : c1.w;
        const float O1r = rb ? c0.z : c1.x, O1i = rb ? c0.w : c1.y;

        const int mr = m & 15, lm = (m >> 4) & 63;
        float pr[16], pim[16];
        if (lm == 0) {
            #pragma unroll
            for (int k = 0; k < 16; ++k) { pr[k] = ar[k ^ mr]; pim[k] = ai[k ^ mr]; }
        } else {
            #pragma unroll
            for (int k = 0; k < 16; ++k) {
                pr[k]  = __shfl_xor(ar[k ^ mr], lm, 64);
                pim[k] = __shfl_xor(ai[k ^ mr], lm, 64);
            }
        }
        #pragma unroll
        for (int k = 0; k < 16; ++k) {
            const int cls = __popc(k & u & 15) & 1;   // compile-time per k
            const float Dr = cls ? D1r : D0r, Di = cls ? D1i : D0i;
            const float Or = cls ? O1r : O0r, Oi = cls ? O1i : O0i;
            float nr = Dr * ar[k] - Di * ai[k] + Or * pr[k] - Oi * pim[k];
            float ni = Dr * ai[k] + Di * ar[k] + Or * pim[k] + Oi * pr[k];
            ar[k] = nr; ai[k] = ni;
        }
    }

    // ---- measurement: E_q = sum |amp|^2 * (-1)^parity(h & mu[q]) ----
    float e[NQ];
    #pragma unroll
    for (int q = 0; q < NQ; ++q) e[q] = 0.0f;
    #pragma unroll
    for (int k = 0; k < 16; ++k) {
        float p2 = ar[k] * ar[k] + ai[k] * ai[k];
        #pragma unroll
        for (int q = 0; q < NQ; ++q) {
            if (__popc(k & TAB.mu[q] & 15) & 1) e[q] -= p2; else e[q] += p2;
        }
    }
    #pragma unroll
    for (int q = 0; q < NQ; ++q) {
        float v = (__popc(tid & (TAB.mu[q] >> 4)) & 1) ? -e[q] : e[q];
        #pragma unroll
        for (int off = 32; off > 0; off >>= 1) v += __shfl_down(v, off, 64);
        e[q] = v;
    }
    __syncthreads();   // lr free for reuse
    if (lane == 0) {
        #pragma unroll
        for (int q = 0; q < NQ; ++q) lr[wave * NQ + q] = e[q];
    }
    __syncthreads();
    if (tid < NCLS) {
        float acc = bias[tid];
        #pragma unroll
        for (int q = 0; q < NQ; ++q) {
            float eq = 0.0f;
            #pragma unroll
            for (int w = 0; w < 16; ++w) eq += lr[w * NQ + q];
            acc += W[tid * NQ + q] * eq;
        }
        out[b * NCLS + tid] = acc;
    }
}

extern "C" void kernel_launch(void* const* d_in, const int* in_sizes, int n_in,
                              void* d_out, int out_size, void* d_ws, size_t ws_size,
                              hipStream_t stream)
{
    const float* x    = (const float*)d_in[0];   // (64, 196)
    const float* W    = (const float*)d_in[1];   // (10, 14)
    const float* bias = (const float*)d_in[2];   // (10,)
    float*       out  = (float*)d_out;           // (64, 10)

    hipLaunchKernelGGL(qvc_kernel, dim3(64), dim3(BLK), 0, stream, x, W, bias, out);
}

// Round 5
// 73.414 us; speedup vs baseline: 3.0463x; 2.3845x over previous
//
#include <hip/hip_runtime.h>

#define NQ     14
#define DIM    16384
#define NPAR   196
#define NCLS   10
#define NGATES 70

// ---------------- compile-time frame/gate tables ----------------
// Stored state d[h] = s_ref[A(h)], A linear over GF(2)^14.
//  - CNOT chain:  s' = s o g, g(i)=i^(i>>1)  =>  A <- g^-1 o A
//  - rotation on ref bit bp: pair h <-> h^m[bp], role = parity(h & u[bp])
//  - physical relabel d'[h]=d[sigma(h)] (bits {0..3}<->{10..13}) => m,u <- sigma(m),sigma(u)
// 5 rounds: phase1 gates (m local: bits 0-9), sigma, phase2 gates (local after sigma).
// Here sigma is realized as the inter-kernel global-memory permutation.
struct GateInfo { int m; int u; int slot; };
struct Tables { GateInfo g[NGATES]; int mu[NQ]; int swap_at[5]; bool valid; };

constexpr unsigned swapbits(unsigned v) {
    return ((v & 0xFu) << 10) | (v & 0x3F0u) | ((v >> 10) & 0xFu);
}

constexpr Tables make_tables() {
    Tables T{};
    T.valid = true;
    unsigned m[NQ] = {}, u[NQ] = {};
    for (int i = 0; i < NQ; ++i) { m[i] = 1u << i; u[i] = 1u << i; }
    int gi = 0;
    for (int r = 0; r < 5; ++r) {
        bool done[NQ] = {};
        for (int q = 0; q < NQ; ++q) {            // phase 1: local now
            int bp = 13 - q;
            if ((m[bp] & 0x3C00u) == 0u) {
                T.g[gi].m = (int)m[bp]; T.g[gi].u = (int)u[bp];
                T.g[gi].slot = r * 14 + q;
                done[q] = true; ++gi;
            }
        }
        T.swap_at[r] = gi;
        if (r > 0 && T.swap_at[r] <= T.swap_at[r - 1]) T.valid = false;
        for (int i = 0; i < NQ; ++i) { m[i] = swapbits(m[i]); u[i] = swapbits(u[i]); }
        for (int q = 0; q < NQ; ++q) {            // phase 2: local after sigma
            if (!done[q]) {
                int bp = 13 - q;
                if ((m[bp] & 0x3C00u) != 0u) T.valid = false;
                T.g[gi].m = (int)m[bp]; T.g[gi].u = (int)u[bp];
                T.g[gi].slot = r * 14 + q;
                ++gi;
            }
        }
        if (r < 4) {                              // CNOT chain retabulation
            for (int bp = 13; bp >= 1; --bp) m[bp] ^= m[bp - 1];
            unsigned acc = 0;
            for (int bp = 13; bp >= 0; --bp) { acc ^= u[bp]; u[bp] = acc; }
        }
    }
    if (gi != NGATES) T.valid = false;
    for (int q = 0; q < NQ; ++q) T.mu[q] = (int)u[13 - q];
    return T;
}
constexpr Tables TAB = make_tables();
static_assert(TAB.valid, "gate schedule construction failed");

constexpr int seg_lo(int s) { return s == 0 ? 0 : TAB.swap_at[s - 1]; }
constexpr int seg_hi(int s) { return s < 5 ? TAB.swap_at[s] : NGATES; }
static_assert(seg_hi(0) - seg_lo(0) <= 32, "seg0");
static_assert(seg_hi(1) - seg_lo(1) <= 32, "seg1");
static_assert(seg_hi(2) - seg_lo(2) <= 32, "seg2");
static_assert(seg_hi(3) - seg_lo(3) <= 32, "seg3");
static_assert(seg_hi(4) - seg_lo(4) <= 32, "seg4");
static_assert(seg_hi(5) - seg_lo(5) <= 32, "seg5");

// ============ multi-kernel path: 256 blocks x 256 threads ============
// h = p<<12 | w<<10 | l<<4 | k   (p: block part, w: wave, l: lane, k: reg)
// Boundary (= sigma): dest(p'=k>>2, w'=k&3, l'=l, k'= p<<2|w)
//   writer: buf[((e*4 + (k>>2))*4 + p)*1024 + ((k&3)<<8 | tid)]
//   reader: buf[((e*4 + p)*4 + (k>>2))*1024 + (w<<8 | (k&3)<<6 | l)]
template<int SEG>
__global__ void __launch_bounds__(256)
qvc_seg(const float* __restrict__ x, const float2* __restrict__ gin,
        float2* __restrict__ gout, float* __restrict__ part)
{
    constexpr int LO = seg_lo(SEG);
    constexpr int HI = seg_hi(SEG);
    constexpr int NG = HI - LO;
    __shared__ __align__(16) float uc[NG][8];
    __shared__ float red[4][NQ];

    const int blk = blockIdx.x;
    const int e = blk >> 2, p = blk & 3;
    const int tid = threadIdx.x;
    const int w = tid >> 6, l = tid & 63;
    const float* xb = x + e * NPAR;

    // gate coefficients: one gate per thread
    if (tid < NG) {
        const int slot = TAB.g[LO + tid].slot;
        const int layer = slot / 14, q = slot % 14;
        const int pidx = (layer < 4) ? layer * 42 + q * 3 : 168 + q * 2;
        float a1 = 0.5f * xb[pidx], a2 = 0.5f * xb[pidx + 1];
        float s1, c1, s2, c2;
        sincosf(a1, &s1, &c1);
        sincosf(a2, &s2, &c2);
        float A00r =  c2 * c1, A00i =  s2 * s1;
        float A01r = -s2 * c1, A01i = -c2 * s1;
        float A10r =  s2 * c1, A10i = -c2 * s1;
        float A11r =  c2 * c1, A11i = -s2 * s1;
        float U0, U1, U2, U3, U4, U5, U6, U7;
        if (layer < 4) {
            float a3 = 0.5f * xb[pidx + 2]; float s3, c3; sincosf(a3, &s3, &c3);
            U0 = c3 * A00r + s3 * A00i; U1 = c3 * A00i - s3 * A00r;
            U2 = c3 * A01r + s3 * A01i; U3 = c3 * A01i - s3 * A01r;
            U4 = c3 * A10r - s3 * A10i; U5 = c3 * A10i + s3 * A10r;
            U6 = c3 * A11r - s3 * A11i; U7 = c3 * A11i + s3 * A11r;
        } else {
            U0 = A00r; U1 = A00i; U2 = A01r; U3 = A01i;
            U4 = A10r; U5 = A10i; U6 = A11r; U7 = A11i;
        }
        uc[tid][0] = U0; uc[tid][1] = U1; uc[tid][2] = U2; uc[tid][3] = U3;
        uc[tid][4] = U4; uc[tid][5] = U5; uc[tid][6] = U6; uc[tid][7] = U7;
    }

    float ar[16], ai[16];
    if constexpr (SEG == 0) {
        #pragma unroll
        for (int k = 0; k < 16; ++k) { ar[k] = 0.0f; ai[k] = 0.0f; }
        if (p == 0 && tid == 0) ar[0] = 1.0f;
    } else {
        #pragma unroll
        for (int k = 0; k < 16; ++k) {
            const int idx = ((e * 4 + p) * 4 + (k >> 2)) * 1024 + (w << 8) + ((k & 3) << 6) + l;
            float2 v = gin[idx];
            ar[k] = v.x; ai[k] = v.y;
        }
    }
    __syncthreads();

    #pragma unroll
    for (int g = LO; g < HI; ++g) {
        const int m = TAB.g[g].m, u = TAB.g[g].u;
        const float4 c0 = *(const float4*)&uc[g - LO][0];  // {00r,00i,01r,01i}
        const float4 c1 = *(const float4*)&uc[g - LO][4];  // {10r,10i,11r,11i}
        const bool rb = (__popc(((p << 8) | tid) & (u >> 4)) & 1) != 0;
        const float D0r = rb ? c1.z : c0.x, D0i = rb ? c1.w : c0.y;
        const float O0r = rb ? c1.x : c0.z, O0i = rb ? c1.y : c0.w;
        const float D1r = rb ? c0.x : c1.z, D1i = rb ? c0.y : c1.w;
        const float O1r = rb ? c0.z : c1.x, O1i = rb ? c0.w : c1.y;

        const int mr = m & 15, lm = (m >> 4) & 63;
        float pr[16], pim[16];
        if (lm == 0) {
            #pragma unroll
            for (int k = 0; k < 16; ++k) { pr[k] = ar[k ^ mr]; pim[k] = ai[k ^ mr]; }
        } else {
            #pragma unroll
            for (int k = 0; k < 16; ++k) {
                pr[k]  = __shfl_xor(ar[k ^ mr], lm, 64);
                pim[k] = __shfl_xor(ai[k ^ mr], lm, 64);
            }
        }
        #pragma unroll
        for (int k = 0; k < 16; ++k) {
            const int cls = __popc(k & u & 15) & 1;   // compile-time per k
            const float Dr = cls ? D1r : D0r, Di = cls ? D1i : D0i;
            const float Or = cls ? O1r : O0r, Oi = cls ? O1i : O0i;
            float nr = Dr * ar[k] - Di * ai[k] + Or * pr[k] - Oi * pim[k];
            float ni = Dr * ai[k] + Di * ar[k] + Or * pim[k] + Oi * pr[k];
            ar[k] = nr; ai[k] = ni;
        }
    }

    if constexpr (SEG < 5) {
        #pragma unroll
        for (int k = 0; k < 16; ++k) {
            const int idx = ((e * 4 + (k >> 2)) * 4 + p) * 1024 + ((k & 3) << 8) + tid;
            gout[idx] = make_float2(ar[k], ai[k]);
        }
    } else {
        // measurement partials: E_qp = sum |amp|^2 * (-1)^parity(h & mu[q])
        float eq[NQ];
        #pragma unroll
        for (int q = 0; q < NQ; ++q) eq[q] = 0.0f;
        #pragma unroll
        for (int k = 0; k < 16; ++k) {
            float p2 = ar[k] * ar[k] + ai[k] * ai[k];
            #pragma unroll
            for (int q = 0; q < NQ; ++q) {
                if (__popc(k & TAB.mu[q] & 15) & 1) eq[q] -= p2; else eq[q] += p2;
            }
        }
        #pragma unroll
        for (int q = 0; q < NQ; ++q) {
            float v = (__popc(((p << 8) | tid) & (TAB.mu[q] >> 4)) & 1) ? -eq[q] : eq[q];
            #pragma unroll
            for (int off = 32; off > 0; off >>= 1) v += __shfl_down(v, off, 64);
            eq[q] = v;
        }
        if (l == 0) {
            #pragma unroll
            for (int q = 0; q < NQ; ++q) red[w][q] = eq[q];
        }
        __syncthreads();
        if (tid < NQ)
            part[(e * 4 + p) * NQ + tid] =
                red[0][tid] + red[1][tid] + red[2][tid] + red[3][tid];
    }
}

__global__ void __launch_bounds__(64)
qvc_head(const float* __restrict__ W, const float* __restrict__ bias,
         const float* __restrict__ part, float* __restrict__ out)
{
    const int e = blockIdx.x, c = threadIdx.x;
    if (c < NCLS) {
        float acc = bias[c];
        const float* pe = part + e * 4 * NQ;
        #pragma unroll
        for (int q = 0; q < NQ; ++q) {
            float eqv = pe[q] + pe[NQ + q] + pe[2 * NQ + q] + pe[3 * NQ + q];
            acc += W[c * NQ + q] * eqv;
        }
        out[e * NCLS + c] = acc;
    }
}

// ============ fallback: round-3 single kernel (64 blocks x 1024) ============
#define BLK 1024
__global__ void __launch_bounds__(BLK)
qvc_fallback(const float* __restrict__ x, const float* __restrict__ W,
             const float* __restrict__ bias, float* __restrict__ out)
{
    __shared__ __align__(16) float lr[DIM];
    __shared__ __align__(16) float li[DIM];
    __shared__ __align__(16) float uc[NGATES][8];

    const int b    = blockIdx.x;
    const int tid  = threadIdx.x;
    const int wave = tid >> 6, lane = tid & 63;
    const float* xb = x + b * NPAR;

    if (tid < NGATES) {
        const int layer = tid / 14, q = tid % 14;
        const int  pidx = (layer < 4) ? layer * 42 + q * 3 : 168 + q * 2;
        float a1 = 0.5f * xb[pidx], a2 = 0.5f * xb[pidx + 1];
        float s1, c1, s2, c2;
        sincosf(a1, &s1, &c1);
        sincosf(a2, &s2, &c2);
        float A00r =  c2 * c1, A00i =  s2 * s1;
        float A01r = -s2 * c1, A01i = -c2 * s1;
        float A10r =  s2 * c1, A10i = -c2 * s1;
        float A11r =  c2 * c1, A11i = -s2 * s1;
        float U0, U1, U2, U3, U4, U5, U6, U7;
        if (layer < 4) {
            float a3 = 0.5f * xb[pidx + 2]; float s3, c3; sincosf(a3, &s3, &c3);
            U0 = c3 * A00r + s3 * A00i; U1 = c3 * A00i - s3 * A00r;
            U2 = c3 * A01r + s3 * A01i; U3 = c3 * A01i - s3 * A01r;
            U4 = c3 * A10r - s3 * A10i; U5 = c3 * A10i + s3 * A10r;
            U6 = c3 * A11r - s3 * A11i; U7 = c3 * A11i + s3 * A11r;
        } else {
            U0 = A00r; U1 = A00i; U2 = A01r; U3 = A01i;
            U4 = A10r; U5 = A10i; U6 = A11r; U7 = A11i;
        }
        uc[tid][0] = U0; uc[tid][1] = U1; uc[tid][2] = U2; uc[tid][3] = U3;
        uc[tid][4] = U4; uc[tid][5] = U5; uc[tid][6] = U6; uc[tid][7] = U7;
    }

    float ar[16], ai[16];
    #pragma unroll
    for (int k = 0; k < 16; ++k) { ar[k] = 0.0f; ai[k] = 0.0f; }
    if (tid == 0) ar[0] = 1.0f;
    __syncthreads();

    #pragma unroll
    for (int g = 0; g < NGATES; ++g) {
        if (g == TAB.swap_at[0] || g == TAB.swap_at[1] || g == TAB.swap_at[2] ||
            g == TAB.swap_at[3] || g == TAB.swap_at[4]) {
            __syncthreads();
            #pragma unroll
            for (int k = 0; k < 16; ++k) {
                lr[wave * 1024 + k * 64 + lane] = ar[k];
                li[wave * 1024 + k * 64 + lane] = ai[k];
            }
            __syncthreads();
            #pragma unroll
            for (int k = 0; k < 16; ++k) {
                ar[k] = lr[k * 1024 + wave * 64 + lane];
                ai[k] = li[k * 1024 + wave * 64 + lane];
            }
        }
        const int m = TAB.g[g].m, u = TAB.g[g].u, slot = TAB.g[g].slot;
        const float4 c0 = *(const float4*)&uc[slot][0];
        const float4 c1 = *(const float4*)&uc[slot][4];
        const bool rb = (__popc(tid & (u >> 4)) & 1) != 0;
        const float D0r = rb ? c1.z : c0.x, D0i = rb ? c1.w : c0.y;
        const float O0r = rb ? c1.x : c0.z, O0i = rb ? c1.y : c0.w;
        const float D1r = rb ? c0.x : c1.z, D1i = rb ? c0.y : c1.w;
        const float O1r = rb ? c0.z : c1.x, O1i = rb ? c0.w : c1.y;

        const int mr = m & 15, lm = (m >> 4) & 63;
        float pr[16], pim[16];
        if (lm == 0) {
            #pragma unroll
            for (int k = 0; k < 16; ++k) { pr[k] = ar[k ^ mr]; pim[k] = ai[k ^ mr]; }
        } else {
            #pragma unroll
            for (int k = 0; k < 16; ++k) {
                pr[k]  = __shfl_xor(ar[k ^ mr], lm, 64);
                pim[k] = __shfl_xor(ai[k ^ mr], lm, 64);
            }
        }
        #pragma unroll
        for (int k = 0; k < 16; ++k) {
            const int cls = __popc(k & u & 15) & 1;
            const float Dr = cls ? D1r : D0r, Di = cls ? D1i : D0i;
            const float Or = cls ? O1r : O0r, Oi = cls ? O1i : O0i;
            float nr = Dr * ar[k] - Di * ai[k] + Or * pr[k] - Oi * pim[k];
            float ni = Dr * ai[k] + Di * ar[k] + Or * pim[k] + Oi * pr[k];
            ar[k] = nr; ai[k] = ni;
        }
    }

    float e[NQ];
    #pragma unroll
    for (int q = 0; q < NQ; ++q) e[q] = 0.0f;
    #pragma unroll
    for (int k = 0; k < 16; ++k) {
        float p2 = ar[k] * ar[k] + ai[k] * ai[k];
        #pragma unroll
        for (int q = 0; q < NQ; ++q) {
            if (__popc(k & TAB.mu[q] & 15) & 1) e[q] -= p2; else e[q] += p2;
        }
    }
    #pragma unroll
    for (int q = 0; q < NQ; ++q) {
        float v = (__popc(tid & (TAB.mu[q] >> 4)) & 1) ? -e[q] : e[q];
        #pragma unroll
        for (int off = 32; off > 0; off >>= 1) v += __shfl_down(v, off, 64);
        e[q] = v;
    }
    __syncthreads();
    if (lane == 0) {
        #pragma unroll
        for (int q = 0; q < NQ; ++q) lr[wave * NQ + q] = e[q];
    }
    __syncthreads();
    if (tid < NCLS) {
        float acc = bias[tid];
        #pragma unroll
        for (int q = 0; q < NQ; ++q) {
            float eqv = 0.0f;
            #pragma unroll
            for (int w = 0; w < 16; ++w) eqv += lr[w * NQ + q];
            acc += W[tid * NQ + q] * eqv;
        }
        out[b * NCLS + tid] = acc;
    }
}

extern "C" void kernel_launch(void* const* d_in, const int* in_sizes, int n_in,
                              void* d_out, int out_size, void* d_ws, size_t ws_size,
                              hipStream_t stream)
{
    const float* x    = (const float*)d_in[0];   // (64, 196)
    const float* W    = (const float*)d_in[1];   // (10, 14)
    const float* bias = (const float*)d_in[2];   // (10,)
    float*       out  = (float*)d_out;           // (64, 10)

    const size_t state_elems = (size_t)64 * DIM;          // float2 each
    const size_t need = 2 * state_elems * sizeof(float2) + 64 * 4 * NQ * sizeof(float);

    if (ws_size >= need) {
        float2* bufA = (float2*)d_ws;
        float2* bufB = bufA + state_elems;
        float*  part = (float*)(bufB + state_elems);

        hipLaunchKernelGGL(qvc_seg<0>, dim3(256), dim3(256), 0, stream, x, (const float2*)nullptr, bufA, (float*)nullptr);
        hipLaunchKernelGGL(qvc_seg<1>, dim3(256), dim3(256), 0, stream, x, bufA, bufB, (float*)nullptr);
        hipLaunchKernelGGL(qvc_seg<2>, dim3(256), dim3(256), 0, stream, x, bufB, bufA, (float*)nullptr);
        hipLaunchKernelGGL(qvc_seg<3>, dim3(256), dim3(256), 0, stream, x, bufA, bufB, (float*)nullptr);
        hipLaunchKernelGGL(qvc_seg<4>, dim3(256), dim3(256), 0, stream, x, bufB, bufA, (float*)nullptr);
        hipLaunchKernelGGL(qvc_seg<5>, dim3(256), dim3(256), 0, stream, x, bufA, (float2*)nullptr, part);
        hipLaunchKernelGGL(qvc_head,   dim3(64),  dim3(64),  0, stream, W, bias, part, out);
    } else {
        hipLaunchKernelGGL(qvc_fallback, dim3(64), dim3(BLK), 0, stream, x, W, bias, out);
    }
}